// Round 7
// baseline (1035.342 us; speedup 1.0000x reference)
//
#include <hip/hip_runtime.h>

// ---------------------------------------------------------------------------
// MLA forward, MI355X (gfx950). FP16 MFMA, f32 accumulate.
// SEQ=4096 EMBED=2048 H=16 QLR=512 KVLR=512 RD=64 VD=128 KD=192
// Round 7: all-reg swapped-QK^T fattn + 2-way kv split per q-block
//          (2 waves/block, LDS merge) -> 16 waves/CU TLP to hide L2 latency.
// ---------------------------------------------------------------------------

#define SEQ   4096
#define EMBED 2048
#define NHEAD 16
#define QLR   512
#define KVLR  512
#define RD    64
#define VD    128
#define KDIM  192

typedef __attribute__((ext_vector_type(8)))  _Float16 half8;
typedef __attribute__((ext_vector_type(4)))  _Float16 half4;
typedef __attribute__((ext_vector_type(4)))  float    f32x4;
typedef __attribute__((ext_vector_type(16))) float    f32x16;
typedef __attribute__((ext_vector_type(2)))  unsigned int uint2v;
typedef __attribute__((ext_vector_type(4)))  unsigned int uint4v;

__device__ __forceinline__ void gload16(void* lds, const void* g) {
    __builtin_amdgcn_global_load_lds(
        (const __attribute__((address_space(1))) void*)g,
        (__attribute__((address_space(3))) void*)lds, 16, 0, 0);
}

__device__ __forceinline__ unsigned int pkh(float a, float b) {
    auto h = __builtin_amdgcn_cvt_pkrtz(a, b);   // __fp16 ext_vector(2)
    return __builtin_bit_cast(unsigned int, h);
}

// ---------------- f32 -> f16 conversion kernels ----------------------------
__global__ __launch_bounds__(256) void cvt_plain(const float* __restrict__ s,
                                                 _Float16* __restrict__ d, int n8) {
    const int i = blockIdx.x * 256 + threadIdx.x;
    if (i >= n8) return;
    const float4 a = reinterpret_cast<const float4*>(s)[i * 2];
    const float4 b = reinterpret_cast<const float4*>(s)[i * 2 + 1];
    half8 r;
    r[0] = (_Float16)a.x; r[1] = (_Float16)a.y; r[2] = (_Float16)a.z; r[3] = (_Float16)a.w;
    r[4] = (_Float16)b.x; r[5] = (_Float16)b.y; r[6] = (_Float16)b.z; r[7] = (_Float16)b.w;
    reinterpret_cast<half8*>(d)[i] = r;
}

__global__ __launch_bounds__(256) void cvt_down(const float* __restrict__ wqd,
                                                const float* __restrict__ wkvd,
                                                const float* __restrict__ wkr,
                                                _Float16* __restrict__ dst) {
    const int i = blockIdx.x * 256 + threadIdx.x;
    if (i >= 1152 * 2048 / 8) return;
    const int e = i * 8, row = e >> 11, col = e & 2047;
    const float* src = row < 512  ? wqd  + (size_t)row * 2048 + col
                     : row < 1024 ? wkvd + (size_t)(row - 512) * 2048 + col
                     : row < 1088 ? wkr  + (size_t)(row - 1024) * 2048 + col
                                  : nullptr;
    half8 r = {};
    if (src) {
        const float4 a = reinterpret_cast<const float4*>(src)[0];
        const float4 b = reinterpret_cast<const float4*>(src)[1];
        r[0] = (_Float16)a.x; r[1] = (_Float16)a.y; r[2] = (_Float16)a.z; r[3] = (_Float16)a.w;
        r[4] = (_Float16)b.x; r[5] = (_Float16)b.y; r[6] = (_Float16)b.z; r[7] = (_Float16)b.w;
    }
    reinterpret_cast<half8*>(dst)[i] = r;
}

__global__ __launch_bounds__(256) void cvt_qup(const float* __restrict__ wqu,
                                               const float* __restrict__ wqr,
                                               _Float16* __restrict__ dst) {
    const int i = blockIdx.x * 256 + threadIdx.x;
    if (i >= 3072 * 512 / 8) return;
    const int e = i * 8, row = e >> 9, col = e & 511;
    const float* src = row < 2048 ? wqu + (size_t)row * 512 + col
                                  : wqr + (size_t)(row - 2048) * 512 + col;
    const float4 a = reinterpret_cast<const float4*>(src)[0];
    const float4 b = reinterpret_cast<const float4*>(src)[1];
    half8 r;
    r[0] = (_Float16)a.x; r[1] = (_Float16)a.y; r[2] = (_Float16)a.z; r[3] = (_Float16)a.w;
    r[4] = (_Float16)b.x; r[5] = (_Float16)b.y; r[6] = (_Float16)b.z; r[7] = (_Float16)b.w;
    reinterpret_cast<half8*>(dst)[i] = r;
}

// ---------------------------------------------------------------------------
// f16 GEMM, m97 structure (unchanged).
// ---------------------------------------------------------------------------
template <int EPI>
__global__ __launch_bounds__(256) void gemm_f16(const _Float16* __restrict__ A,
                                                const _Float16* __restrict__ B,
                                                _Float16* __restrict__ o0,
                                                _Float16* __restrict__ o1,
                                                _Float16* __restrict__ o2,
                                                float* __restrict__ of,
                                                int M, int N, int K)
{
    __shared__ _Float16 sA[128 * 64];
    __shared__ _Float16 sB[128 * 64];

    const int tid  = threadIdx.x;
    const int wid  = tid >> 6;
    const int lane = tid & 63;
    const int lr   = lane & 15;
    const int lg   = lane >> 4;
    const int row0 = blockIdx.y * 128;
    const int col0 = blockIdx.x * 128;
    const int war  = (wid >> 1) * 64;
    const int wac  = (wid & 1) * 64;

    const int sr = lane >> 3;
    const int sk = (lane & 7) * 8;
    const _Float16* Ab = A + (size_t)(row0 + wid * 8 + sr) * K + sk;
    const _Float16* Bb = B + (size_t)(col0 + wid * 8 + sr) * K + sk;

    f32x4 acc[4][4] = {};

    for (int k0 = 0; k0 < K; k0 += 64) {
#pragma unroll
        for (int i = 0; i < 4; ++i) {
            const int c = i * 4 + wid;
            gload16((char*)sA + c * 1024, Ab + (size_t)i * 32 * K + k0);
            gload16((char*)sB + c * 1024, Bb + (size_t)i * 32 * K + k0);
        }
        __syncthreads();

#pragma unroll
        for (int kk = 0; kk < 64; kk += 32) {
            half8 a[4], b[4];
#pragma unroll
            for (int i = 0; i < 4; ++i)
                a[i] = *reinterpret_cast<const half8*>(&sA[(war + i * 16 + lr) * 64 + kk + lg * 8]);
#pragma unroll
            for (int j = 0; j < 4; ++j)
                b[j] = *reinterpret_cast<const half8*>(&sB[(wac + j * 16 + lr) * 64 + kk + lg * 8]);
            __builtin_amdgcn_s_setprio(1);
#pragma unroll
            for (int i = 0; i < 4; ++i)
#pragma unroll
                for (int j = 0; j < 4; ++j)
                    acc[i][j] = __builtin_amdgcn_mfma_f32_16x16x32_f16(a[i], b[j], acc[i][j], 0, 0, 0);
            __builtin_amdgcn_s_setprio(0);
        }
        __syncthreads();
    }

#pragma unroll
    for (int i = 0; i < 4; ++i)
#pragma unroll
        for (int j = 0; j < 4; ++j) {
            const int grow0 = row0 + war + i * 16 + lg * 4;
            const int gcol  = col0 + wac + j * 16 + lr;
            if constexpr (EPI == 2) {
                if (gcol >= 2048) {
                    half4 pv;
#pragma unroll
                    for (int r = 0; r < 4; ++r) pv[r] = (_Float16)acc[i][j][r];
                    *reinterpret_cast<half4*>(&o1[(size_t)(gcol - 2048) * SEQ + grow0]) = pv;
                    continue;
                }
            }
#pragma unroll
            for (int r = 0; r < 4; ++r) {
                const int grow = grow0 + r;
                const float v = acc[i][j][r];
                if constexpr (EPI == 0) {
                    if (gcol < 512)       o0[(size_t)grow * 512 + gcol] = (_Float16)v;
                    else if (gcol < 1024) o1[(size_t)grow * 512 + gcol - 512] = (_Float16)v;
                    else if (gcol < 1088) o2[(size_t)grow * 64 + gcol - 1024] = (_Float16)v;
                } else if constexpr (EPI == 1) {
                    if (gcol < 2048)
                        o0[(size_t)grow * (NHEAD * KDIM) + (gcol >> 7) * KDIM + (gcol & 127)] = (_Float16)v;
                    else {
                        const int c = gcol - 2048;
                        o0[(size_t)grow * (NHEAD * KDIM) + (c >> 6) * KDIM + VD + (c & 63)] = (_Float16)v;
                    }
                } else if constexpr (EPI == 2) {
                    o0[((size_t)(gcol >> 7) * SEQ + grow) * KDIM + (gcol & 127)] = (_Float16)v;
                } else {
                    of[(size_t)grow * N + gcol] = v;
                }
            }
        }
}

// ---------------------------------------------------------------------------
// RoPE: q in place (qfin[s][h*192+...]); shared k -> kfin[h][s][128+...].
// ---------------------------------------------------------------------------
__global__ __launch_bounds__(256) void rope_kernel(_Float16* __restrict__ qf,
                                                   _Float16* __restrict__ kf,
                                                   const _Float16* __restrict__ ktmp)
{
    __shared__ float s_sin[32], s_cos[32];
    const int s   = blockIdx.x;
    const int tid = threadIdx.x;
    if (tid < 32) {
        const double inv = exp(-(double)tid * (log(10000.0) / 32.0));
        const double ang = (double)s * inv;
        s_sin[tid] = (float)sin(ang);
        s_cos[tid] = (float)cos(ang);
    }
    __syncthreads();

    for (int p = tid; p < NHEAD * 32; p += 256) {
        const int h = p >> 5, i = p & 31;
        const size_t base = (size_t)s * (NHEAD * KDIM) + h * KDIM + VD;
        const float x1 = (float)qf[base + i];
        const float x2 = (float)qf[base + 32 + i];
        const float cs = s_cos[i], sn = s_sin[i];
        qf[base + i]      = (_Float16)(x1 * cs - x2 * sn);
        qf[base + 32 + i] = (_Float16)(x2 * cs + x1 * sn);
    }
    if (tid < 32) {
        const int i = tid;
        const float x1 = (float)ktmp[(size_t)s * RD + i];
        const float x2 = (float)ktmp[(size_t)s * RD + 32 + i];
        const float cs = s_cos[i], sn = s_sin[i];
        const _Float16 r1 = (_Float16)(x1 * cs - x2 * sn);
        const _Float16 r2 = (_Float16)(x2 * cs + x1 * sn);
#pragma unroll
        for (int h = 0; h < NHEAD; ++h) {
            const size_t base = ((size_t)h * SEQ + s) * KDIM + VD;
            kf[base + i]      = r1;
            kf[base + 32 + i] = r2;
        }
    }
}

// ---------------------------------------------------------------------------
// Flash attention, all-register math + 2-way kv split.
// Block = 128 threads (2 waves) for 32 q-cols of one head.
// Wave 0: kv tiles [0, n0); wave 1: [n0, nt) incl. diagonal. Final merge of
// (m,l,O) via LDS — per-lane scalar (O^T frag layout is lane-local).
// Swapped QK^T: S^T[kv][q] = K·Q (mfma_32x32x16); in-lane softmax;
// P -> PV B-frag via cvt_pkrtz + permlane32_swap; V direct from vT.
// ---------------------------------------------------------------------------
__global__ __launch_bounds__(128, 4) void fattn(const _Float16* __restrict__ qf,
                                                const _Float16* __restrict__ kf,
                                                const _Float16* __restrict__ vT,
                                                _Float16* __restrict__ attn)
{
    __shared__ float mrg[64][66];          // wave1's O (64) + m + l  (16.9 KB)

    const int idx = blockIdx.x;
    const int h   = idx & 15;              // same-head blocks share XCD (idx%8)
    const int qb  = 127 - (idx >> 4);      // heavy q-blocks first
    const int q0w = qb * 32;

    const int wid  = threadIdx.x >> 6;     // kv-split half
    const int lane = threadIdx.x & 63;
    const int l31  = lane & 31;
    const int h5   = lane >> 5;
    const int qg   = q0w + l31;            // this lane's q column

    const float scale = 0.0721687836487032f;   // 1/sqrt(192)

    // ---- persistent Q B-frags: col q = l31, k-slot = ks*16 + h5*8 ----
    half8 qfr[12];
    {
        const _Float16* qb_ = qf + (size_t)qg * (NHEAD * KDIM) + h * KDIM + h5 * 8;
#pragma unroll
        for (int ks = 0; ks < 12; ++ks)
            qfr[ks] = *reinterpret_cast<const half8*>(qb_ + ks * 16);
    }

    const _Float16* kb0 = kf + ((size_t)h * SEQ + l31) * KDIM + h5 * 8;
    const _Float16* kb1 = kb0 + (size_t)32 * KDIM;
    const _Float16* vb  = vT + ((size_t)h * VD + l31) * SEQ + h5 * 8;

    f32x16 o0 = {}, o1 = {}, o2 = {}, o3 = {};   // O^T d-blocks 0..3
    float m_ = -1e30f, l_ = 0.0f;

    const int nt = (qb >> 1) + 1;
    const int n0 = (nt + 1) >> 1;
    const int tbeg = wid ? n0 : 0;
    const int tend = wid ? nt : n0;

    for (int t = tbeg; t < tend; ++t) {
        const int j0 = t * 64;

        // ---- S^T = K · Q ----
        f32x16 s0 = {}, s1 = {};
        {
            const _Float16* k0 = kb0 + (size_t)j0 * KDIM;
            const _Float16* k1 = kb1 + (size_t)j0 * KDIM;
            __builtin_amdgcn_s_setprio(1);
#pragma unroll
            for (int ks = 0; ks < 12; ++ks) {
                const half8 ka = *reinterpret_cast<const half8*>(k0 + ks * 16);
                const half8 kb = *reinterpret_cast<const half8*>(k1 + ks * 16);
                s0 = __builtin_amdgcn_mfma_f32_32x32x16_f16(ka, qfr[ks], s0, 0, 0, 0);
                s1 = __builtin_amdgcn_mfma_f32_32x32x16_f16(kb, qfr[ks], s1, 0, 0, 0);
            }
            __builtin_amdgcn_s_setprio(0);
        }

        // ---- issue V loads for d0=0 now (latency hides under softmax) ----
        half8 vfA[4], vfB[4];
#pragma unroll
        for (int ks = 0; ks < 4; ++ks)
            vfA[ks] = *reinterpret_cast<const half8*>(vb + j0 + ks * 16);

        // ---- scale + causal mask ----
#pragma unroll
        for (int m = 0; m < 16; ++m) { s0[m] *= scale; s1[m] *= scale; }
        if (j0 + 63 > q0w) {
#pragma unroll
            for (int m = 0; m < 16; ++m) {
                const int kv = j0 + (m & 3) + 8 * (m >> 2) + 4 * h5;
                if (kv > qg)      s0[m] = -3.0e38f;
                if (kv + 32 > qg) s1[m] = -3.0e38f;
            }
        }

        // ---- row max: in-lane + one cross-half swap ----
        float mx = s0[0];
#pragma unroll
        for (int m = 1; m < 16; ++m) mx = fmaxf(mx, s0[m]);
#pragma unroll
        for (int m = 0; m < 16; ++m) mx = fmaxf(mx, s1[m]);
        mx = fmaxf(mx, __shfl_xor(mx, 32, 64));

        // ---- defer-max online softmax ----
        if (!__all(mx - m_ <= 8.0f)) {
            const float mn = fmaxf(m_, mx);
            const float alpha = __expf(m_ - mn);
            m_ = mn;
            l_ *= alpha;
#pragma unroll
            for (int m = 0; m < 16; ++m) {
                o0[m] *= alpha; o1[m] *= alpha; o2[m] *= alpha; o3[m] *= alpha;
            }
        }
        float rs = 0.0f;
#pragma unroll
        for (int m = 0; m < 16; ++m) { const float p = __expf(s0[m] - m_); s0[m] = p; rs += p; }
#pragma unroll
        for (int m = 0; m < 16; ++m) { const float p = __expf(s1[m] - m_); s1[m] = p; rs += p; }
        rs += __shfl_xor(rs, 32, 64);
        l_ += rs;

        // ---- assemble P B-frags: cvt_pkrtz + permlane32_swap ----
        half8 pb[4];
#pragma unroll
        for (int ks16 = 0; ks16 < 4; ++ks16) {
            const int base = (ks16 & 1) * 8;
            unsigned int x, x2, y, y2;
            if (ks16 < 2) {
                x  = pkh(s0[base + 0], s0[base + 1]);
                x2 = pkh(s0[base + 2], s0[base + 3]);
                y  = pkh(s0[base + 4], s0[base + 5]);
                y2 = pkh(s0[base + 6], s0[base + 7]);
            } else {
                x  = pkh(s1[base + 0], s1[base + 1]);
                x2 = pkh(s1[base + 2], s1[base + 3]);
                y  = pkh(s1[base + 4], s1[base + 5]);
                y2 = pkh(s1[base + 6], s1[base + 7]);
            }
            const uint2v r1 = __builtin_amdgcn_permlane32_swap(x,  y,  false, false);
            const uint2v r2 = __builtin_amdgcn_permlane32_swap(x2, y2, false, false);
            const uint4v u = { r1[0], r2[0], r1[1], r2[1] };   // j01,j23,j45,j67
            pb[ks16] = __builtin_bit_cast(half8, u);
        }

        // ---- O^T += V^T · P, rolling per-d0 V window ----
        __builtin_amdgcn_s_setprio(1);
#pragma unroll
        for (int ks = 0; ks < 4; ++ks)
            vfB[ks] = *reinterpret_cast<const half8*>(vb + 32 * SEQ + j0 + ks * 16);
#pragma unroll
        for (int ks = 0; ks < 4; ++ks)
            o0 = __builtin_amdgcn_mfma_f32_32x32x16_f16(vfA[ks], pb[ks], o0, 0, 0, 0);
#pragma unroll
        for (int ks = 0; ks < 4; ++ks)
            vfA[ks] = *reinterpret_cast<const half8*>(vb + 64 * SEQ + j0 + ks * 16);
#pragma unroll
        for (int ks = 0; ks < 4; ++ks)
            o1 = __builtin_amdgcn_mfma_f32_32x32x16_f16(vfB[ks], pb[ks], o1, 0, 0, 0);
#pragma unroll
        for (int ks = 0; ks < 4; ++ks)
            vfB[ks] = *reinterpret_cast<const half8*>(vb + 96 * SEQ + j0 + ks * 16);
#pragma unroll
        for (int ks = 0; ks < 4; ++ks)
            o2 = __builtin_amdgcn_mfma_f32_32x32x16_f16(vfA[ks], pb[ks], o2, 0, 0, 0);
#pragma unroll
        for (int ks = 0; ks < 4; ++ks)
            o3 = __builtin_amdgcn_mfma_f32_32x32x16_f16(vfB[ks], pb[ks], o3, 0, 0, 0);
        __builtin_amdgcn_s_setprio(0);
    }

    // ---- merge the two kv halves: wave1 -> LDS, wave0 combines ----
    if (wid == 1) {
#pragma unroll
        for (int m = 0; m < 16; ++m) {
            mrg[lane][m]      = o0[m];
            mrg[lane][16 + m] = o1[m];
            mrg[lane][32 + m] = o2[m];
            mrg[lane][48 + m] = o3[m];
        }
        mrg[lane][64] = m_;
        mrg[lane][65] = l_;
    }
    __syncthreads();
    if (wid != 0) return;

    {
        const float m1 = mrg[lane][64];
        const float l1 = mrg[lane][65];
        const float ms = fmaxf(m_, m1);
        const float a0 = __expf(m_ - ms);
        const float a1 = __expf(m1 - ms);   // m1=-1e30 (empty) -> 0
        l_ = l_ * a0 + l1 * a1;
#pragma unroll
        for (int m = 0; m < 16; ++m) {
            o0[m] = o0[m] * a0 + mrg[lane][m]      * a1;
            o1[m] = o1[m] * a0 + mrg[lane][16 + m] * a1;
            o2[m] = o2[m] * a0 + mrg[lane][32 + m] * a1;
            o3[m] = o3[m] * a0 + mrg[lane][48 + m] * a1;
        }
    }

    // ---- normalize + store: pack reg pairs (d, d+1) -> u32 ----
    const float invl = 1.0f / l_;
    _Float16* ob = attn + (size_t)qg * (NHEAD * VD) + h * VD + 4 * h5;
#pragma unroll
    for (int g = 0; g < 4; ++g) {
#pragma unroll
        for (int pp = 0; pp < 2; ++pp) {
            const int m = g * 4 + pp * 2;
            const int dof = pp * 2 + 8 * g;
            *reinterpret_cast<unsigned int*>(ob + dof) =
                pkh(o0[m] * invl, o0[m + 1] * invl);
            *reinterpret_cast<unsigned int*>(ob + 32 + dof) =
                pkh(o1[m] * invl, o1[m + 1] * invl);
            *reinterpret_cast<unsigned int*>(ob + 64 + dof) =
                pkh(o2[m] * invl, o2[m + 1] * invl);
            *reinterpret_cast<unsigned int*>(ob + 96 + dof) =
                pkh(o3[m] * invl, o3[m + 1] * invl);
        }
    }
}

// ---------------------------------------------------------------------------
extern "C" void kernel_launch(void* const* d_in, const int* in_sizes, int n_in,
                              void* d_out, int out_size, void* d_ws, size_t ws_size,
                              hipStream_t stream)
{
    (void)in_sizes; (void)n_in; (void)out_size; (void)ws_size;
    const float* x    = (const float*)d_in[0];
    const float* wqd  = (const float*)d_in[2];
    const float* wqu  = (const float*)d_in[3];
    const float* wqr  = (const float*)d_in[4];
    const float* wkvd = (const float*)d_in[5];
    const float* wkvu = (const float*)d_in[6];
    const float* wkr  = (const float*)d_in[7];
    const float* wout = (const float*)d_in[8];
    float* out = (float*)d_out;

    char* ws = (char*)d_ws;
    _Float16* x_h    = (_Float16*)ws; ws += (size_t)SEQ * EMBED * 2;
    _Float16* wdownh = (_Float16*)ws; ws += (size_t)1152 * EMBED * 2;
    _Float16* wquph  = (_Float16*)ws; ws += (size_t)3072 * QLR * 2;
    _Float16* wkvuh  = (_Float16*)ws; ws += (size_t)4096 * KVLR * 2;
    _Float16* c_q    = (_Float16*)ws; ws += (size_t)SEQ * QLR * 2;
    _Float16* c_kv   = (_Float16*)ws; ws += (size_t)SEQ * KVLR * 2;
    _Float16* ktmp   = (_Float16*)ws; ws += (size_t)SEQ * RD * 2;
    _Float16* qfin   = (_Float16*)ws; ws += (size_t)SEQ * NHEAD * KDIM * 2;
    _Float16* kfin   = (_Float16*)ws; ws += (size_t)SEQ * NHEAD * KDIM * 2;  // [h][s][192]
    _Float16* vT     = (_Float16*)ws; ws += (size_t)NHEAD * VD * SEQ * 2;    // [h*128+d][s]
    _Float16* attn   = x_h;      // alias (x_h dead after G1)
    _Float16* wouth  = c_q;      // alias (c_q dead after G2)

    dim3 blk(256);

    cvt_plain<<<dim3(4096), blk, 0, stream>>>(x, x_h, SEQ * EMBED / 8);
    cvt_down <<<dim3(1152), blk, 0, stream>>>(wqd, wkvd, wkr, wdownh);
    cvt_qup  <<<dim3(768),  blk, 0, stream>>>(wqu, wqr, wquph);
    cvt_plain<<<dim3(1024), blk, 0, stream>>>(wkvu, wkvuh, 4096 * KVLR / 8);

    // G1: x @ [wqd;wkvd;wkr]^T -> c_q, c_kv, ktmp
    gemm_f16<0><<<dim3(9, 32), blk, 0, stream>>>(
        x_h, wdownh, c_q, c_kv, ktmp, nullptr, SEQ, 1152, EMBED);
    // G2: c_q @ [wqu;wqr]^T -> qfin
    gemm_f16<1><<<dim3(24, 32), blk, 0, stream>>>(
        c_q, wquph, qfin, nullptr, nullptr, nullptr, SEQ, 3072, QLR);
    // G3: c_kv @ wkvu^T -> kfin (per-head), vT
    gemm_f16<2><<<dim3(32, 32), blk, 0, stream>>>(
        c_kv, wkvuh, kfin, vT, nullptr, nullptr, SEQ, 4096, KVLR);

    cvt_plain<<<dim3(2048), blk, 0, stream>>>(wout, wouth, EMBED * EMBED / 8);

    rope_kernel<<<dim3(SEQ), blk, 0, stream>>>(qfin, kfin, ktmp);
    // attention: 2048 blocks x 2 waves (kv split), heavy-first
    fattn<<<dim3(2048), dim3(128), 0, stream>>>(qfin, kfin, vT, attn);
    // G4: attn @ wout^T -> out (f32)
    gemm_f16<3><<<dim3(16, 32), blk, 0, stream>>>(
        attn, wouth, nullptr, nullptr, nullptr, out, SEQ, EMBED, NHEAD * VD);
}

// Round 8
// 335.107 us; speedup vs baseline: 3.0896x; 3.0896x over previous
//
#include <hip/hip_runtime.h>

// ---------------------------------------------------------------------------
// MLA forward, MI355X (gfx950). FP16 MFMA, f32 accumulate.
// SEQ=4096 EMBED=2048 H=16 QLR=512 KVLR=512 RD=64 VD=128 KD=192
// Round 8: fattn = LDS-staged K/V (round-4 pipeline: gload_lds, pre-swizzled
//          src, dbuf-K + single-buf V) x in-register math (round-7: swapped
//          QK^T 32x32x16, in-lane softmax, P via cvt_pkrtz+permlane32_swap).
//          4 waves x 32 q-cols, 64 KB LDS -> 2 blocks/CU. No P round-trip.
// ---------------------------------------------------------------------------

#define SEQ   4096
#define EMBED 2048
#define NHEAD 16
#define QLR   512
#define KVLR  512
#define RD    64
#define VD    128
#define KDIM  192

typedef __attribute__((ext_vector_type(8)))  _Float16 half8;
typedef __attribute__((ext_vector_type(4)))  _Float16 half4;
typedef __attribute__((ext_vector_type(4)))  float    f32x4;
typedef __attribute__((ext_vector_type(16))) float    f32x16;
typedef __attribute__((ext_vector_type(2)))  unsigned int uint2v;
typedef __attribute__((ext_vector_type(4)))  unsigned int uint4v;

__device__ __forceinline__ void gload16(void* lds, const void* g) {
    __builtin_amdgcn_global_load_lds(
        (const __attribute__((address_space(1))) void*)g,
        (__attribute__((address_space(3))) void*)lds, 16, 0, 0);
}

__device__ __forceinline__ unsigned int pkh(float a, float b) {
    auto h = __builtin_amdgcn_cvt_pkrtz(a, b);   // __fp16 ext_vector(2)
    return __builtin_bit_cast(unsigned int, h);
}

// ---------------- f32 -> f16 conversion kernels ----------------------------
__global__ __launch_bounds__(256) void cvt_plain(const float* __restrict__ s,
                                                 _Float16* __restrict__ d, int n8) {
    const int i = blockIdx.x * 256 + threadIdx.x;
    if (i >= n8) return;
    const float4 a = reinterpret_cast<const float4*>(s)[i * 2];
    const float4 b = reinterpret_cast<const float4*>(s)[i * 2 + 1];
    half8 r;
    r[0] = (_Float16)a.x; r[1] = (_Float16)a.y; r[2] = (_Float16)a.z; r[3] = (_Float16)a.w;
    r[4] = (_Float16)b.x; r[5] = (_Float16)b.y; r[6] = (_Float16)b.z; r[7] = (_Float16)b.w;
    reinterpret_cast<half8*>(d)[i] = r;
}

__global__ __launch_bounds__(256) void cvt_down(const float* __restrict__ wqd,
                                                const float* __restrict__ wkvd,
                                                const float* __restrict__ wkr,
                                                _Float16* __restrict__ dst) {
    const int i = blockIdx.x * 256 + threadIdx.x;
    if (i >= 1152 * 2048 / 8) return;
    const int e = i * 8, row = e >> 11, col = e & 2047;
    const float* src = row < 512  ? wqd  + (size_t)row * 2048 + col
                     : row < 1024 ? wkvd + (size_t)(row - 512) * 2048 + col
                     : row < 1088 ? wkr  + (size_t)(row - 1024) * 2048 + col
                                  : nullptr;
    half8 r = {};
    if (src) {
        const float4 a = reinterpret_cast<const float4*>(src)[0];
        const float4 b = reinterpret_cast<const float4*>(src)[1];
        r[0] = (_Float16)a.x; r[1] = (_Float16)a.y; r[2] = (_Float16)a.z; r[3] = (_Float16)a.w;
        r[4] = (_Float16)b.x; r[5] = (_Float16)b.y; r[6] = (_Float16)b.z; r[7] = (_Float16)b.w;
    }
    reinterpret_cast<half8*>(dst)[i] = r;
}

__global__ __launch_bounds__(256) void cvt_qup(const float* __restrict__ wqu,
                                               const float* __restrict__ wqr,
                                               _Float16* __restrict__ dst) {
    const int i = blockIdx.x * 256 + threadIdx.x;
    if (i >= 3072 * 512 / 8) return;
    const int e = i * 8, row = e >> 9, col = e & 511;
    const float* src = row < 2048 ? wqu + (size_t)row * 512 + col
                                  : wqr + (size_t)(row - 2048) * 512 + col;
    const float4 a = reinterpret_cast<const float4*>(src)[0];
    const float4 b = reinterpret_cast<const float4*>(src)[1];
    half8 r;
    r[0] = (_Float16)a.x; r[1] = (_Float16)a.y; r[2] = (_Float16)a.z; r[3] = (_Float16)a.w;
    r[4] = (_Float16)b.x; r[5] = (_Float16)b.y; r[6] = (_Float16)b.z; r[7] = (_Float16)b.w;
    reinterpret_cast<half8*>(dst)[i] = r;
}

// ---------------------------------------------------------------------------
// f16 GEMM, m97 structure (unchanged).
// ---------------------------------------------------------------------------
template <int EPI>
__global__ __launch_bounds__(256) void gemm_f16(const _Float16* __restrict__ A,
                                                const _Float16* __restrict__ B,
                                                _Float16* __restrict__ o0,
                                                _Float16* __restrict__ o1,
                                                _Float16* __restrict__ o2,
                                                float* __restrict__ of,
                                                int M, int N, int K)
{
    __shared__ _Float16 sA[128 * 64];
    __shared__ _Float16 sB[128 * 64];

    const int tid  = threadIdx.x;
    const int wid  = tid >> 6;
    const int lane = tid & 63;
    const int lr   = lane & 15;
    const int lg   = lane >> 4;
    const int row0 = blockIdx.y * 128;
    const int col0 = blockIdx.x * 128;
    const int war  = (wid >> 1) * 64;
    const int wac  = (wid & 1) * 64;

    const int sr = lane >> 3;
    const int sk = (lane & 7) * 8;
    const _Float16* Ab = A + (size_t)(row0 + wid * 8 + sr) * K + sk;
    const _Float16* Bb = B + (size_t)(col0 + wid * 8 + sr) * K + sk;

    f32x4 acc[4][4] = {};

    for (int k0 = 0; k0 < K; k0 += 64) {
#pragma unroll
        for (int i = 0; i < 4; ++i) {
            const int c = i * 4 + wid;
            gload16((char*)sA + c * 1024, Ab + (size_t)i * 32 * K + k0);
            gload16((char*)sB + c * 1024, Bb + (size_t)i * 32 * K + k0);
        }
        __syncthreads();

#pragma unroll
        for (int kk = 0; kk < 64; kk += 32) {
            half8 a[4], b[4];
#pragma unroll
            for (int i = 0; i < 4; ++i)
                a[i] = *reinterpret_cast<const half8*>(&sA[(war + i * 16 + lr) * 64 + kk + lg * 8]);
#pragma unroll
            for (int j = 0; j < 4; ++j)
                b[j] = *reinterpret_cast<const half8*>(&sB[(wac + j * 16 + lr) * 64 + kk + lg * 8]);
            __builtin_amdgcn_s_setprio(1);
#pragma unroll
            for (int i = 0; i < 4; ++i)
#pragma unroll
                for (int j = 0; j < 4; ++j)
                    acc[i][j] = __builtin_amdgcn_mfma_f32_16x16x32_f16(a[i], b[j], acc[i][j], 0, 0, 0);
            __builtin_amdgcn_s_setprio(0);
        }
        __syncthreads();
    }

#pragma unroll
    for (int i = 0; i < 4; ++i)
#pragma unroll
        for (int j = 0; j < 4; ++j) {
            const int grow0 = row0 + war + i * 16 + lg * 4;
            const int gcol  = col0 + wac + j * 16 + lr;
            if constexpr (EPI == 2) {
                if (gcol >= 2048) {
                    half4 pv;
#pragma unroll
                    for (int r = 0; r < 4; ++r) pv[r] = (_Float16)acc[i][j][r];
                    *reinterpret_cast<half4*>(&o1[(size_t)(gcol - 2048) * SEQ + grow0]) = pv;
                    continue;
                }
            }
#pragma unroll
            for (int r = 0; r < 4; ++r) {
                const int grow = grow0 + r;
                const float v = acc[i][j][r];
                if constexpr (EPI == 0) {
                    if (gcol < 512)       o0[(size_t)grow * 512 + gcol] = (_Float16)v;
                    else if (gcol < 1024) o1[(size_t)grow * 512 + gcol - 512] = (_Float16)v;
                    else if (gcol < 1088) o2[(size_t)grow * 64 + gcol - 1024] = (_Float16)v;
                } else if constexpr (EPI == 1) {
                    if (gcol < 2048)
                        o0[(size_t)grow * (NHEAD * KDIM) + (gcol >> 7) * KDIM + (gcol & 127)] = (_Float16)v;
                    else {
                        const int c = gcol - 2048;
                        o0[(size_t)grow * (NHEAD * KDIM) + (c >> 6) * KDIM + VD + (c & 63)] = (_Float16)v;
                    }
                } else if constexpr (EPI == 2) {
                    o0[((size_t)(gcol >> 7) * SEQ + grow) * KDIM + (gcol & 127)] = (_Float16)v;
                } else {
                    of[(size_t)grow * N + gcol] = v;
                }
            }
        }
}

// ---------------------------------------------------------------------------
// RoPE: q in place (qfin[s][h*192+...]); shared k -> kfin[h][s][128+...].
// ---------------------------------------------------------------------------
__global__ __launch_bounds__(256) void rope_kernel(_Float16* __restrict__ qf,
                                                   _Float16* __restrict__ kf,
                                                   const _Float16* __restrict__ ktmp)
{
    __shared__ float s_sin[32], s_cos[32];
    const int s   = blockIdx.x;
    const int tid = threadIdx.x;
    if (tid < 32) {
        const double inv = exp(-(double)tid * (log(10000.0) / 32.0));
        const double ang = (double)s * inv;
        s_sin[tid] = (float)sin(ang);
        s_cos[tid] = (float)cos(ang);
    }
    __syncthreads();

    for (int p = tid; p < NHEAD * 32; p += 256) {
        const int h = p >> 5, i = p & 31;
        const size_t base = (size_t)s * (NHEAD * KDIM) + h * KDIM + VD;
        const float x1 = (float)qf[base + i];
        const float x2 = (float)qf[base + 32 + i];
        const float cs = s_cos[i], sn = s_sin[i];
        qf[base + i]      = (_Float16)(x1 * cs - x2 * sn);
        qf[base + 32 + i] = (_Float16)(x2 * cs + x1 * sn);
    }
    if (tid < 32) {
        const int i = tid;
        const float x1 = (float)ktmp[(size_t)s * RD + i];
        const float x2 = (float)ktmp[(size_t)s * RD + 32 + i];
        const float cs = s_cos[i], sn = s_sin[i];
        const _Float16 r1 = (_Float16)(x1 * cs - x2 * sn);
        const _Float16 r2 = (_Float16)(x2 * cs + x1 * sn);
#pragma unroll
        for (int h = 0; h < NHEAD; ++h) {
            const size_t base = ((size_t)h * SEQ + s) * KDIM + VD;
            kf[base + i]      = r1;
            kf[base + 32 + i] = r2;
        }
    }
}

// ---------------------------------------------------------------------------
// Causal flash attention: 256 threads (4 waves), 128 q-cols/block (32/wave).
// KV step 64. K double-buffered (2x24 KB), V single-buffered (16 KB) in LDS,
// both staged by global_load_lds with pre-swizzled global sources
// (granule G stored at G^(row&7); reads apply same XOR).
// Math all-register: S^T = K·Q (mfma_32x32x16, A=K-frag from LDS, B=Q regs);
// in-lane softmax (32 regs + 1 shfl_xor(32)); defer-max; P assembled via
// cvt_pkrtz + permlane32_swap; PV: O^T += V^T·P with V A-frags from LDS.
// Schedule/step: issue K[t+1] -> QK -> softmax -> barrier(drain V[t],K[t+1])
//                -> PV -> barrier -> issue V[t+1].
// ---------------------------------------------------------------------------
__global__ __launch_bounds__(256, 2) void fattn(const _Float16* __restrict__ qf,
                                                const _Float16* __restrict__ kf,
                                                const _Float16* __restrict__ vT,
                                                _Float16* __restrict__ attn)
{
    __shared__ _Float16 sK[2][64 * 192];   // 48 KB
    __shared__ _Float16 sV[128 * 64];      // 16 KB

    const int idx = blockIdx.x;
    const int h   = idx & 15;
    const int qt  = 31 - (idx >> 4);       // heavy first
    const int q0  = qt * 128;

    const int tid  = threadIdx.x;
    const int wid  = tid >> 6;
    const int lane = tid & 63;
    const int l31  = lane & 31;
    const int h5   = lane >> 5;
    const int x7   = l31 & 7;
    const int qg   = q0 + wid * 32 + l31;  // this lane's q column
    const int q0w  = q0 + wid * 32;

    const float scale = 0.0721687836487032f;   // 1/sqrt(192)

    // ---- K staging: 24 chunks of 1KB; wave chunk c = wid*6+i ----
    const _Float16* ksrc[6];
    int klds[6];
#pragma unroll
    for (int i = 0; i < 6; ++i) {
        const int c   = wid * 6 + i;
        const int gi  = c * 64 + lane;
        const int row = gi / 24;
        const int g   = gi % 24;
        ksrc[i] = kf + ((size_t)h * SEQ + row) * KDIM + ((g ^ (row & 7)) << 3);
        klds[i] = c * 1024;
    }
    // ---- V staging: 16 chunks; wave chunk c = wid*4+i ----
    const _Float16* vsrc[4];
    int vlds[4];
#pragma unroll
    for (int i = 0; i < 4; ++i) {
        const int c = wid * 4 + i;
        const int d = c * 8 + (lane >> 3);
        vsrc[i] = vT + ((size_t)h * VD + d) * SEQ + (((lane & 7) ^ (lane >> 3)) << 3);
        vlds[i] = c * 1024;
    }

    // ---- persistent Q B-frags: col q = l31, k-slot = ks*16 + h5*8 ----
    half8 qfr[12];
    {
        const _Float16* qb_ = qf + (size_t)qg * (NHEAD * KDIM) + h * KDIM + h5 * 8;
#pragma unroll
        for (int ks = 0; ks < 12; ++ks)
            qfr[ks] = *reinterpret_cast<const half8*>(qb_ + ks * 16);
    }

    f32x16 o0 = {}, o1 = {}, o2 = {}, o3 = {};
    float m_ = -1e30f, l_ = 0.0f;

    const int nt = 2 * qt + 2;

    // prologue: K[0] -> buf0, V[0]
    {
#pragma unroll
        for (int i = 0; i < 6; ++i) gload16((char*)sK[0] + klds[i], ksrc[i]);
#pragma unroll
        for (int i = 0; i < 4; ++i) gload16((char*)sV + vlds[i], vsrc[i]);
    }
    __syncthreads();

    int cur = 0;
    for (int t = 0; t < nt; ++t) {
        const int j0 = t * 64;

        // ---- issue K[t+1] into the other buffer ----
        if (t + 1 < nt) {
            const size_t joff = (size_t)(j0 + 64) * KDIM;
#pragma unroll
            for (int i = 0; i < 6; ++i)
                gload16((char*)sK[cur ^ 1] + klds[i], ksrc[i] + joff);
        }

        // ---- S^T = K · Q  (A-frags from LDS, swizzled) ----
        f32x16 s0 = {}, s1 = {};
        {
            const char* kb = (const char*)sK[cur];
            __builtin_amdgcn_s_setprio(1);
#pragma unroll
            for (int ks = 0; ks < 12; ++ks) {
                const int go = ((ks * 2 + h5) ^ x7) << 4;
                const half8 ka = *reinterpret_cast<const half8*>(kb + l31 * 384 + go);
                const half8 kc = *reinterpret_cast<const half8*>(kb + (32 + l31) * 384 + go);
                s0 = __builtin_amdgcn_mfma_f32_32x32x16_f16(ka, qfr[ks], s0, 0, 0, 0);
                s1 = __builtin_amdgcn_mfma_f32_32x32x16_f16(kc, qfr[ks], s1, 0, 0, 0);
            }
            __builtin_amdgcn_s_setprio(0);
        }

        // ---- scale + causal mask ----
#pragma unroll
        for (int m = 0; m < 16; ++m) { s0[m] *= scale; s1[m] *= scale; }
        if (j0 + 63 > q0w) {
#pragma unroll
            for (int m = 0; m < 16; ++m) {
                const int kv = j0 + (m & 3) + 8 * (m >> 2) + 4 * h5;
                if (kv > qg)      s0[m] = -3.0e38f;
                if (kv + 32 > qg) s1[m] = -3.0e38f;
            }
        }

        // ---- row max: in-lane + one cross-half swap ----
        float mx = s0[0];
#pragma unroll
        for (int m = 1; m < 16; ++m) mx = fmaxf(mx, s0[m]);
#pragma unroll
        for (int m = 0; m < 16; ++m) mx = fmaxf(mx, s1[m]);
        mx = fmaxf(mx, __shfl_xor(mx, 32, 64));

        // ---- defer-max online softmax ----
        if (!__all(mx - m_ <= 8.0f)) {
            const float mn = fmaxf(m_, mx);
            const float alpha = __expf(m_ - mn);
            m_ = mn;
            l_ *= alpha;
#pragma unroll
            for (int m = 0; m < 16; ++m) {
                o0[m] *= alpha; o1[m] *= alpha; o2[m] *= alpha; o3[m] *= alpha;
            }
        }
        float rs = 0.0f;
#pragma unroll
        for (int m = 0; m < 16; ++m) { const float p = __expf(s0[m] - m_); s0[m] = p; rs += p; }
#pragma unroll
        for (int m = 0; m < 16; ++m) { const float p = __expf(s1[m] - m_); s1[m] = p; rs += p; }
        rs += __shfl_xor(rs, 32, 64);
        l_ += rs;

        // ---- assemble P B-frags (cvt_pkrtz + permlane32_swap) ----
        half8 pb0, pb1, pb2, pb3;
        {
            unsigned int x, x2, y, y2;
            x  = pkh(s0[0], s0[1]);  x2 = pkh(s0[2], s0[3]);
            y  = pkh(s0[4], s0[5]);  y2 = pkh(s0[6], s0[7]);
            uint2v r1 = __builtin_amdgcn_permlane32_swap(x, y, false, false);
            uint2v r2 = __builtin_amdgcn_permlane32_swap(x2, y2, false, false);
            { uint4v u = { r1[0], r2[0], r1[1], r2[1] }; pb0 = __builtin_bit_cast(half8, u); }
            x  = pkh(s0[8], s0[9]);  x2 = pkh(s0[10], s0[11]);
            y  = pkh(s0[12], s0[13]); y2 = pkh(s0[14], s0[15]);
            r1 = __builtin_amdgcn_permlane32_swap(x, y, false, false);
            r2 = __builtin_amdgcn_permlane32_swap(x2, y2, false, false);
            { uint4v u = { r1[0], r2[0], r1[1], r2[1] }; pb1 = __builtin_bit_cast(half8, u); }
            x  = pkh(s1[0], s1[1]);  x2 = pkh(s1[2], s1[3]);
            y  = pkh(s1[4], s1[5]);  y2 = pkh(s1[6], s1[7]);
            r1 = __builtin_amdgcn_permlane32_swap(x, y, false, false);
            r2 = __builtin_amdgcn_permlane32_swap(x2, y2, false, false);
            { uint4v u = { r1[0], r2[0], r1[1], r2[1] }; pb2 = __builtin_bit_cast(half8, u); }
            x  = pkh(s1[8], s1[9]);  x2 = pkh(s1[10], s1[11]);
            y  = pkh(s1[12], s1[13]); y2 = pkh(s1[14], s1[15]);
            r1 = __builtin_amdgcn_permlane32_swap(x, y, false, false);
            r2 = __builtin_amdgcn_permlane32_swap(x2, y2, false, false);
            { uint4v u = { r1[0], r2[0], r1[1], r2[1] }; pb3 = __builtin_bit_cast(half8, u); }
        }

        // barrier #1: V[t] (and K[t+1]) complete + all waves done reading K[cur]
        __syncthreads();

        // ---- O^T += V^T · P  (V A-frags from LDS, swizzled) ----
        {
            const char* vbse = (const char*)sV;
            __builtin_amdgcn_s_setprio(1);
#pragma unroll
            for (int ks = 0; ks < 4; ++ks) {
                const int go = ((ks * 2 + h5) ^ x7) << 4;
                const half8 pbk = ks == 0 ? pb0 : ks == 1 ? pb1 : ks == 2 ? pb2 : pb3;
                const half8 v0 = *reinterpret_cast<const half8*>(vbse + (l31)      * 128 + go);
                const half8 v1 = *reinterpret_cast<const half8*>(vbse + (32 + l31) * 128 + go);
                const half8 v2 = *reinterpret_cast<const half8*>(vbse + (64 + l31) * 128 + go);
                const half8 v3 = *reinterpret_cast<const half8*>(vbse + (96 + l31) * 128 + go);
                o0 = __builtin_amdgcn_mfma_f32_32x32x16_f16(v0, pbk, o0, 0, 0, 0);
                o1 = __builtin_amdgcn_mfma_f32_32x32x16_f16(v1, pbk, o1, 0, 0, 0);
                o2 = __builtin_amdgcn_mfma_f32_32x32x16_f16(v2, pbk, o2, 0, 0, 0);
                o3 = __builtin_amdgcn_mfma_f32_32x32x16_f16(v3, pbk, o3, 0, 0, 0);
            }
            __builtin_amdgcn_s_setprio(0);
        }

        // barrier #2: all waves done reading V -> safe to overwrite
        __syncthreads();

        // ---- issue V[t+1] ----
        if (t + 1 < nt) {
            const int jn = j0 + 64;
#pragma unroll
            for (int i = 0; i < 4; ++i)
                gload16((char*)sV + vlds[i], vsrc[i] + jn);
        }
        cur ^= 1;
    }

    // ---- normalize + store ----
    const float invl = 1.0f / l_;
    _Float16* ob = attn + (size_t)qg * (NHEAD * VD) + h * VD + 4 * h5;
#pragma unroll
    for (int g = 0; g < 4; ++g) {
#pragma unroll
        for (int pp = 0; pp < 2; ++pp) {
            const int m = g * 4 + pp * 2;
            const int dof = pp * 2 + 8 * g;
            *reinterpret_cast<unsigned int*>(ob + dof) =
                pkh(o0[m] * invl, o0[m + 1] * invl);
            *reinterpret_cast<unsigned int*>(ob + 32 + dof) =
                pkh(o1[m] * invl, o1[m + 1] * invl);
            *reinterpret_cast<unsigned int*>(ob + 64 + dof) =
                pkh(o2[m] * invl, o2[m + 1] * invl);
            *reinterpret_cast<unsigned int*>(ob + 96 + dof) =
                pkh(o3[m] * invl, o3[m + 1] * invl);
        }
    }
}

// ---------------------------------------------------------------------------
extern "C" void kernel_launch(void* const* d_in, const int* in_sizes, int n_in,
                              void* d_out, int out_size, void* d_ws, size_t ws_size,
                              hipStream_t stream)
{
    (void)in_sizes; (void)n_in; (void)out_size; (void)ws_size;
    const float* x    = (const float*)d_in[0];
    const float* wqd  = (const float*)d_in[2];
    const float* wqu  = (const float*)d_in[3];
    const float* wqr  = (const float*)d_in[4];
    const float* wkvd = (const float*)d_in[5];
    const float* wkvu = (const float*)d_in[6];
    const float* wkr  = (const float*)d_in[7];
    const float* wout = (const float*)d_in[8];
    float* out = (float*)d_out;

    char* ws = (char*)d_ws;
    _Float16* x_h    = (_Float16*)ws; ws += (size_t)SEQ * EMBED * 2;
    _Float16* wdownh = (_Float16*)ws; ws += (size_t)1152 * EMBED * 2;
    _Float16* wquph  = (_Float16*)ws; ws += (size_t)3072 * QLR * 2;
    _Float16* wkvuh  = (_Float16*)ws; ws += (size_t)4096 * KVLR * 2;
    _Float16* c_q    = (_Float16*)ws; ws += (size_t)SEQ * QLR * 2;
    _Float16* c_kv   = (_Float16*)ws; ws += (size_t)SEQ * KVLR * 2;
    _Float16* ktmp   = (_Float16*)ws; ws += (size_t)SEQ * RD * 2;
    _Float16* qfin   = (_Float16*)ws; ws += (size_t)SEQ * NHEAD * KDIM * 2;
    _Float16* kfin   = (_Float16*)ws; ws += (size_t)SEQ * NHEAD * KDIM * 2;  // [h][s][192]
    _Float16* vT     = (_Float16*)ws; ws += (size_t)NHEAD * VD * SEQ * 2;    // [h*128+d][s]
    _Float16* attn   = x_h;      // alias (x_h dead after G1)
    _Float16* wouth  = c_q;      // alias (c_q dead after G2)

    dim3 blk(256);

    cvt_plain<<<dim3(4096), blk, 0, stream>>>(x, x_h, SEQ * EMBED / 8);
    cvt_down <<<dim3(1152), blk, 0, stream>>>(wqd, wkvd, wkr, wdownh);
    cvt_qup  <<<dim3(768),  blk, 0, stream>>>(wqu, wqr, wquph);
    cvt_plain<<<dim3(1024), blk, 0, stream>>>(wkvu, wkvuh, 4096 * KVLR / 8);

    // G1: x @ [wqd;wkvd;wkr]^T -> c_q, c_kv, ktmp
    gemm_f16<0><<<dim3(9, 32), blk, 0, stream>>>(
        x_h, wdownh, c_q, c_kv, ktmp, nullptr, SEQ, 1152, EMBED);
    // G2: c_q @ [wqu;wqr]^T -> qfin
    gemm_f16<1><<<dim3(24, 32), blk, 0, stream>>>(
        c_q, wquph, qfin, nullptr, nullptr, nullptr, SEQ, 3072, QLR);
    // G3: c_kv @ wkvu^T -> kfin (per-head), vT
    gemm_f16<2><<<dim3(32, 32), blk, 0, stream>>>(
        c_kv, wkvuh, kfin, vT, nullptr, nullptr, SEQ, 4096, KVLR);

    cvt_plain<<<dim3(2048), blk, 0, stream>>>(wout, wouth, EMBED * EMBED / 8);

    rope_kernel<<<dim3(SEQ), blk, 0, stream>>>(qfin, kfin, ktmp);
    // attention: 512 blocks x 4 waves, heavy-first
    fattn<<<dim3(512), blk, 0, stream>>>(qfin, kfin, vT, attn);
    // G4: attn @ wout^T -> out (f32)
    gemm_f16<3><<<dim3(16, 32), blk, 0, stream>>>(
        attn, wouth, nullptr, nullptr, nullptr, out, SEQ, EMBED, NHEAD * VD);
}